// Round 1
// baseline (7583.740 us; speedup 1.0000x reference)
//
#include <hip/hip_runtime.h>
#include <hip/hip_bf16.h>
#include <math.h>

#define B_      2
#define L_      2048
#define H_      16
#define DK_     64
#define DMODEL_ 1024
#define LN_EPS  1e-5f
#define ROWS    8          // rows per block in FC/LN kernel

// ---------------------------------------------------------------------------
// Kernel 1: attention. One block per (b, h, q-row). 256 threads.
//  - scores = (q . k) / sqrt(64) for all 2048 k
//  - softmax (block reduction), write attn row (coalesced)
//  - PV: out[d] = sum_k p[k] * V[k,d], wave g handles contiguous k-chunk
// ---------------------------------------------------------------------------
__global__ __launch_bounds__(256) void attn_kernel(
    const float* __restrict__ Q, const float* __restrict__ K,
    const float* __restrict__ V, float* __restrict__ attn_out,
    float* __restrict__ head_out)
{
    const int qi  = blockIdx.x;
    const int h   = blockIdx.y;
    const int b   = blockIdx.z;
    const int tid = threadIdx.x;

    __shared__ float q_s[DK_];
    __shared__ float p_s[L_];
    __shared__ float red_s[256];

    if (tid < DK_)
        q_s[tid] = Q[((size_t)(b * L_ + qi)) * DMODEL_ + h * DK_ + tid];
    __syncthreads();

    // q row into registers (broadcast LDS reads, 16 x float4 = 64 VGPR)
    float4 qv[16];
    {
        const float4* q4 = (const float4*)q_s;
        #pragma unroll
        for (int j = 0; j < 16; ++j) qv[j] = q4[j];
    }

    // ---- phase 1: scores + running max (8 k-rows per thread) ----
    float sc[8];
    float lmax = -1e30f;
    #pragma unroll 2
    for (int i = 0; i < 8; ++i) {
        const int kk = i * 256 + tid;
        const float4* kp =
            (const float4*)(K + ((size_t)(b * L_ + kk)) * DMODEL_ + h * DK_);
        float acc = 0.f;
        #pragma unroll
        for (int j = 0; j < 16; ++j) {
            float4 kv = kp[j];
            acc = fmaf(kv.x, qv[j].x, acc);
            acc = fmaf(kv.y, qv[j].y, acc);
            acc = fmaf(kv.z, qv[j].z, acc);
            acc = fmaf(kv.w, qv[j].w, acc);
        }
        sc[i] = acc * 0.125f;          // 1/sqrt(64)
        lmax  = fmaxf(lmax, sc[i]);
    }

    // block max reduction
    red_s[tid] = lmax;
    __syncthreads();
    #pragma unroll
    for (int s = 128; s > 0; s >>= 1) {
        if (tid < s) red_s[tid] = fmaxf(red_s[tid], red_s[tid + s]);
        __syncthreads();
    }
    const float rmax = red_s[0];
    __syncthreads();

    // exp + block sum reduction
    float lsum = 0.f;
    #pragma unroll
    for (int i = 0; i < 8; ++i) {
        float e = __expf(sc[i] - rmax);
        sc[i]  = e;
        lsum  += e;
    }
    red_s[tid] = lsum;
    __syncthreads();
    #pragma unroll
    for (int s = 128; s > 0; s >>= 1) {
        if (tid < s) red_s[tid] += red_s[tid + s];
        __syncthreads();
    }
    const float inv = 1.0f / red_s[0];
    __syncthreads();

    // normalize, stash in LDS, write attn row (coalesced 1KB/wave-instr)
    float* arow = attn_out + (((size_t)(b * H_ + h)) * L_ + qi) * (size_t)L_;
    #pragma unroll
    for (int i = 0; i < 8; ++i) {
        const int kk = i * 256 + tid;
        const float p = sc[i] * inv;
        p_s[kk]  = p;
        arow[kk] = p;
    }
    __syncthreads();

    // ---- phase 2: PV. wave g = tid>>6 takes k in [g*512, g*512+512) ----
    const int d = tid & 63;
    const int g = tid >> 6;
    const float* vp = V + ((size_t)b * L_) * DMODEL_ + h * DK_ + d;
    float acc = 0.f;
    const int k0 = g * 512;
    #pragma unroll 8
    for (int kk = k0; kk < k0 + 512; ++kk) {
        acc = fmaf(p_s[kk], vp[(size_t)kk * DMODEL_], acc);
    }
    red_s[tid] = acc;
    __syncthreads();
    if (tid < 64) {
        float o = red_s[tid] + red_s[tid + 64] + red_s[tid + 128] + red_s[tid + 192];
        head_out[((size_t)(b * L_ + qi)) * DMODEL_ + h * DK_ + tid] = o;
    }
}

// ---------------------------------------------------------------------------
// Kernel 2: out = LayerNorm(head_out @ W + b + residual) * gamma + beta
// ROWS rows per block (amortize W traffic through L2). 256 threads,
// thread t owns output cols {t, t+256, t+512, t+768}.
// ---------------------------------------------------------------------------
__global__ __launch_bounds__(256) void fc_ln_kernel(
    const float* __restrict__ X,      // [B*L, 1024] head outputs
    const float* __restrict__ W,      // [1024, 1024]
    const float* __restrict__ bias,   // [1024]
    const float* __restrict__ Qres,   // [B*L, 1024] residual (= q input)
    const float* __restrict__ gamma,
    const float* __restrict__ beta,
    float* __restrict__ Out)          // [B*L, 1024]
{
    const int r0  = blockIdx.x * ROWS;
    const int tid = threadIdx.x;

    __shared__ float  xs[ROWS][DMODEL_];
    __shared__ float2 red2_s[256];

    for (int idx = tid; idx < ROWS * DMODEL_; idx += 256) {
        const int r = idx >> 10, c = idx & 1023;
        xs[r][c] = X[(size_t)(r0 + r) * DMODEL_ + c];
    }
    __syncthreads();

    float acc[ROWS][4];
    #pragma unroll
    for (int r = 0; r < ROWS; ++r)
        #pragma unroll
        for (int c = 0; c < 4; ++c) acc[r][c] = 0.f;

    for (int i = 0; i < DMODEL_; ++i) {
        const float* wr = W + (size_t)i * DMODEL_;
        const float w0 = wr[tid];
        const float w1 = wr[tid + 256];
        const float w2 = wr[tid + 512];
        const float w3 = wr[tid + 768];
        #pragma unroll
        for (int r = 0; r < ROWS; ++r) {
            const float xi = xs[r][i];
            acc[r][0] = fmaf(xi, w0, acc[r][0]);
            acc[r][1] = fmaf(xi, w1, acc[r][1]);
            acc[r][2] = fmaf(xi, w2, acc[r][2]);
            acc[r][3] = fmaf(xi, w3, acc[r][3]);
        }
    }

    // bias / gamma / beta per owned column
    float bb[4], gg[4], be[4];
    #pragma unroll
    for (int c = 0; c < 4; ++c) {
        bb[c] = bias[tid + c * 256];
        gg[c] = gamma[tid + c * 256];
        be[c] = beta[tid + c * 256];
    }

    for (int r = 0; r < ROWS; ++r) {
        const size_t rowoff = (size_t)(r0 + r) * DMODEL_;
        float y[4];
        float s = 0.f, s2 = 0.f;
        #pragma unroll
        for (int c = 0; c < 4; ++c) {
            y[c] = acc[r][c] + bb[c] + Qres[rowoff + tid + c * 256];
            s  += y[c];
            s2 += y[c] * y[c];
        }
        red2_s[tid] = make_float2(s, s2);
        __syncthreads();
        #pragma unroll
        for (int st = 128; st > 0; st >>= 1) {
            if (tid < st) {
                red2_s[tid].x += red2_s[tid + st].x;
                red2_s[tid].y += red2_s[tid + st].y;
            }
            __syncthreads();
        }
        const float mu   = red2_s[0].x * (1.f / DMODEL_);
        const float var  = red2_s[0].y * (1.f / DMODEL_) - mu * mu;
        const float rstd = rsqrtf(var + LN_EPS);
        __syncthreads();   // protect red2_s before next row overwrites

        #pragma unroll
        for (int c = 0; c < 4; ++c) {
            Out[rowoff + tid + c * 256] = (y[c] - mu) * rstd * gg[c] + be[c];
        }
    }
}

// ---------------------------------------------------------------------------
extern "C" void kernel_launch(void* const* d_in, const int* in_sizes, int n_in,
                              void* d_out, int out_size, void* d_ws, size_t ws_size,
                              hipStream_t stream)
{
    const float* q     = (const float*)d_in[0];
    const float* k     = (const float*)d_in[1];
    const float* v     = (const float*)d_in[2];
    const float* W_fc  = (const float*)d_in[3];
    const float* b_fc  = (const float*)d_in[4];
    const float* gamma = (const float*)d_in[5];
    const float* beta  = (const float*)d_in[6];

    float* out  = (float*)d_out;                          // [B, L, 1024]
    float* attn = out + (size_t)B_ * L_ * DMODEL_;        // [B, H, L, L]
    float* head_out = (float*)d_ws;                       // [B, L, 1024] scratch

    dim3 g1(L_, H_, B_);   // q fastest -> blocks sharing (b,h) reuse K/V in L2
    attn_kernel<<<g1, 256, 0, stream>>>(q, k, v, attn, head_out);

    fc_ln_kernel<<<(B_ * L_) / ROWS, 256, 0, stream>>>(
        head_out, W_fc, b_fc, q, gamma, beta, out);
}

// Round 3
// 985.211 us; speedup vs baseline: 7.6976x; 7.6976x over previous
//
#include <hip/hip_runtime.h>
#include <hip/hip_bf16.h>
#include <math.h>

#define B_      2
#define L_      2048
#define H_      16
#define DMODEL_ 1024
#define LN_EPS  1e-5f
#define ROWS    16

typedef __attribute__((ext_vector_type(8))) __bf16 bf16x8;
typedef __attribute__((ext_vector_type(8))) short  short8;
typedef __attribute__((ext_vector_type(4))) float  f32x4;

typedef const __attribute__((address_space(1))) void cgvoid_t;
typedef __attribute__((address_space(3))) void svoid_t;

__device__ __forceinline__ void gload16(const void* g, void* l) {
    __builtin_amdgcn_global_load_lds((cgvoid_t*)g, (svoid_t*)l, 16, 0, 0);
}

__device__ __forceinline__ short f2bf(float x) {
    __hip_bfloat16 h = __float2bfloat16(x);
    return __builtin_bit_cast(short, h);
}
__device__ __forceinline__ float bf2f(short s) {
    unsigned u = ((unsigned)(unsigned short)s) << 16;
    return __builtin_bit_cast(float, u);
}
__device__ __forceinline__ f32x4 mfma16(bf16x8 a, bf16x8 b, f32x4 c) {
    return __builtin_amdgcn_mfma_f32_16x16x32_bf16(a, b, c, 0, 0, 0);
}

// ---------------------------------------------------------------------------
// prep_qk: [B,L,H*64] f32 -> [B,H,L,64] bf16, 16B chunks XOR-swizzled within
// each 128B row (chunk c stored at position c ^ (l&7)) so linear
// global_load_lds staging produces the swizzled LDS tile directly.
// ---------------------------------------------------------------------------
__global__ __launch_bounds__(256) void prep_qk(const float* __restrict__ src,
                                               short* __restrict__ dst)
{
    const int t = blockIdx.x * 256 + threadIdx.x;      // B*H*L*8 chunks
    const int c = t & 7, l = (t >> 3) & 2047, h = (t >> 14) & 15, b = t >> 18;
    const float* s = src + ((size_t)(b * L_ + l)) * DMODEL_ + h * 64 + c * 8;
    float4 f0 = *(const float4*)s;
    float4 f1 = *(const float4*)(s + 4);
    short8 o;
    o[0] = f2bf(f0.x); o[1] = f2bf(f0.y); o[2] = f2bf(f0.z); o[3] = f2bf(f0.w);
    o[4] = f2bf(f1.x); o[5] = f2bf(f1.y); o[6] = f2bf(f1.z); o[7] = f2bf(f1.w);
    short* d = dst + ((size_t)((b * H_ + h) * L_ + l)) * 64 + (c ^ (l & 7)) * 8;
    *(short8*)d = o;
}

// ---------------------------------------------------------------------------
// prep_v: [B,L,H*64] f32 -> [B,H,64,L] bf16 (transposed per head), chunk
// swizzle applied within each 64-k tile of each d-row.
// ---------------------------------------------------------------------------
__global__ __launch_bounds__(256) void prep_v(const float* __restrict__ src,
                                              short* __restrict__ dst)
{
    const int blk = blockIdx.x;                 // (b*16+h)*64 + g
    const int g = blk & 63, h = (blk >> 6) & 15, b = blk >> 10;
    const int d = threadIdx.x & 63, lc = g * 4 + (threadIdx.x >> 6);
    const int l0 = lc * 8;
    const float* s = src + ((size_t)(b * L_ + l0)) * DMODEL_ + h * 64 + d;
    short8 o;
    #pragma unroll
    for (int j = 0; j < 8; ++j) o[j] = f2bf(s[(size_t)j * DMODEL_]);
    short* dp = dst + ((size_t)((b * H_ + h) * 64 + d)) * L_
              + (l0 & ~63) + (((lc & 7) ^ (d & 7)) * 8);
    *(short8*)dp = o;
}

// ---------------------------------------------------------------------------
// attn_mfma: block = (b, h, 64 q-rows). 4 waves, wave w owns q rows w*16..+15.
// Pass 1: QK^T (MFMA) + exp -> row sums.  Pass 2: recompute, write normalized
// attn (nontemporal), P->bf16 LDS, PV MFMA, write head bf16.
// ---------------------------------------------------------------------------
__global__ __launch_bounds__(256) void attn_mfma(
    const short* __restrict__ Qb, const short* __restrict__ Kb,
    const short* __restrict__ Vb, float* __restrict__ attn,
    short* __restrict__ head)
{
    const int qt = blockIdx.x, h = blockIdx.y, b = blockIdx.z;
    const int tid = threadIdx.x;
    const int lane = tid & 63, w = tid >> 6;
    const int kgrp = lane >> 4, l15 = lane & 15;
    const int bh = b * H_ + h;
    const int q0 = qt * 64;

    __shared__ short qe_s[64 * 64];        // Q tile, later reused as P tile
    __shared__ short k2_s[2 * 64 * 64];    // K double buffer
    __shared__ short v2_s[2 * 64 * 64];    // V^T double buffer

    const char* Qg = (const char*)(Qb + ((size_t)bh * L_ + q0) * 64);
    const char* Kg = (const char*)(Kb + (size_t)bh * L_ * 64);
    const char* Vg = (const char*)(Vb + (size_t)bh * 64 * L_);

    // stage Q tile (8KB linear copy; swizzle pre-applied in memory)
    gload16(Qg + (w * 64 + lane) * 16, (char*)qe_s + w * 1024 + lane * 16);
    gload16(Qg + 4096 + (w * 64 + lane) * 16,
            (char*)qe_s + 4096 + w * 1024 + lane * 16);
    __syncthreads();

    const int arow = w * 16 + l15;
    bf16x8 aq0 = *(const bf16x8*)((const char*)qe_s + arow * 128 + ((kgrp ^ (arow & 7)) * 16));
    bf16x8 aq1 = *(const bf16x8*)((const char*)qe_s + arow * 128 + (((kgrp + 4) ^ (arow & 7)) * 16));
    __syncthreads();

    auto stageK = [&](int kt, int bu) {
        const char* kg = Kg + (size_t)kt * 8192;
        char* lk = (char*)k2_s + bu * 8192;
        gload16(kg + (w * 64 + lane) * 16, lk + w * 1024 + lane * 16);
        gload16(kg + 4096 + (w * 64 + lane) * 16, lk + 4096 + w * 1024 + lane * 16);
    };
    auto stageV = [&](int kt, int bu) {
        const char* vg = Vg + (size_t)kt * 128;
        char* lv = (char*)v2_s + bu * 8192;
        int cid = w * 64 + lane;
        gload16(vg + (size_t)(cid >> 3) * 4096 + (cid & 7) * 16, lv + w * 1024 + lane * 16);
        cid += 256;
        gload16(vg + (size_t)(cid >> 3) * 4096 + (cid & 7) * 16, lv + 4096 + w * 1024 + lane * 16);
    };

    // ---------------- pass 1: row sums ----------------
    float rsum[4] = {0.f, 0.f, 0.f, 0.f};
    stageK(0, 0);
    __syncthreads();
    int buf = 0;
    for (int kt = 0; kt < 32; ++kt) {
        if (kt < 31) stageK(kt + 1, buf ^ 1);
        const char* ks = (const char*)k2_s + buf * 8192;
        #pragma unroll
        for (int t = 0; t < 4; ++t) {
            const int brow = t * 16 + l15;
            f32x4 acc = {0.f, 0.f, 0.f, 0.f};
            bf16x8 b0 = *(const bf16x8*)(ks + brow * 128 + ((kgrp ^ (brow & 7)) * 16));
            bf16x8 b1 = *(const bf16x8*)(ks + brow * 128 + (((kgrp + 4) ^ (brow & 7)) * 16));
            acc = mfma16(aq0, b0, acc);
            acc = mfma16(aq1, b1, acc);
            #pragma unroll
            for (int r = 0; r < 4; ++r) rsum[r] += __expf(acc[r] * 0.125f);
        }
        __syncthreads();
        buf ^= 1;
    }
    #pragma unroll
    for (int m = 1; m < 16; m <<= 1) {
        #pragma unroll
        for (int r = 0; r < 4; ++r) rsum[r] += __shfl_xor(rsum[r], m, 64);
    }
    float rinv[4];
    #pragma unroll
    for (int r = 0; r < 4; ++r) rinv[r] = 1.0f / rsum[r];

    // ---------------- pass 2: attn write + PV ----------------
    f32x4 oacc[4];
    #pragma unroll
    for (int t = 0; t < 4; ++t) oacc[t] = (f32x4){0.f, 0.f, 0.f, 0.f};

    float* arow_p = attn + ((size_t)bh * L_ + (q0 + w * 16 + kgrp * 4)) * L_;

    stageK(0, 0);
    stageV(0, 0);
    __syncthreads();
    buf = 0;
    for (int kt = 0; kt < 32; ++kt) {
        if (kt < 31) { stageK(kt + 1, buf ^ 1); stageV(kt + 1, buf ^ 1); }
        const char* ks = (const char*)k2_s + buf * 8192;
        const char* vs = (const char*)v2_s + buf * 8192;
        #pragma unroll
        for (int t = 0; t < 4; ++t) {
            const int brow = t * 16 + l15;
            f32x4 acc = {0.f, 0.f, 0.f, 0.f};
            bf16x8 b0 = *(const bf16x8*)(ks + brow * 128 + ((kgrp ^ (brow & 7)) * 16));
            bf16x8 b1 = *(const bf16x8*)(ks + brow * 128 + (((kgrp + 4) ^ (brow & 7)) * 16));
            acc = mfma16(aq0, b0, acc);
            acc = mfma16(aq1, b1, acc);
            #pragma unroll
            for (int r = 0; r < 4; ++r) {
                float e = __expf(acc[r] * 0.125f) * rinv[r];
                __builtin_nontemporal_store(e, arow_p + (size_t)r * L_ + kt * 64 + t * 16 + l15);
                const int row = w * 16 + kgrp * 4 + r, col = t * 16 + l15;
                *(short*)((char*)qe_s + row * 128 + (((col >> 3) ^ (row & 7)) * 16) + (col & 7) * 2) = f2bf(e);
            }
        }
        __syncthreads();
        // PV: A = P tile (qe_s), B = V^T tile
        bf16x8 ae0 = *(const bf16x8*)((const char*)qe_s + arow * 128 + ((kgrp ^ (arow & 7)) * 16));
        bf16x8 ae1 = *(const bf16x8*)((const char*)qe_s + arow * 128 + (((kgrp + 4) ^ (arow & 7)) * 16));
        #pragma unroll
        for (int t = 0; t < 4; ++t) {
            const int brow = t * 16 + l15;   // d index
            bf16x8 v0 = *(const bf16x8*)(vs + brow * 128 + ((kgrp ^ (brow & 7)) * 16));
            bf16x8 v1 = *(const bf16x8*)(vs + brow * 128 + (((kgrp + 4) ^ (brow & 7)) * 16));
            oacc[t] = mfma16(ae0, v0, oacc[t]);
            oacc[t] = mfma16(ae1, v1, oacc[t]);
        }
        __syncthreads();
        buf ^= 1;
    }

    #pragma unroll
    for (int t = 0; t < 4; ++t)
        #pragma unroll
        for (int r = 0; r < 4; ++r)
            head[(size_t)(b * L_ + q0 + w * 16 + kgrp * 4 + r) * DMODEL_
                 + h * 64 + t * 16 + l15] = f2bf(oacc[t][r]);
}

// ---------------------------------------------------------------------------
// fc_ln: out = LN(head @ W + b + residual); head is bf16.
// ROWS=16 rows/block halves W L3 traffic vs 8. Per-row stats via wave
// shfl_xor reduce + one barrier (no log-tree barriers).
// ---------------------------------------------------------------------------
__global__ __launch_bounds__(256) void fc_ln_kernel(
    const short* __restrict__ X,
    const float* __restrict__ W,
    const float* __restrict__ bias,
    const float* __restrict__ Qres,
    const float* __restrict__ gamma,
    const float* __restrict__ beta,
    float* __restrict__ Out)
{
    const int r0   = blockIdx.x * ROWS;
    const int tid  = threadIdx.x;
    const int lane = tid & 63, wv = tid >> 6;

    __shared__ float  xs[ROWS][DMODEL_];
    __shared__ float2 part_s[ROWS][4];

    for (int idx = tid; idx < ROWS * (DMODEL_ / 8); idx += 256) {
        const int r = idx >> 7, c8 = idx & 127;
        short8 v8 = *(const short8*)(X + (size_t)(r0 + r) * DMODEL_ + c8 * 8);
        #pragma unroll
        for (int j = 0; j < 8; ++j) xs[r][c8 * 8 + j] = bf2f(v8[j]);
    }
    __syncthreads();

    float acc[ROWS][4];
    #pragma unroll
    for (int r = 0; r < ROWS; ++r)
        #pragma unroll
        for (int c = 0; c < 4; ++c) acc[r][c] = 0.f;

    for (int i = 0; i < DMODEL_; ++i) {
        const float* wr = W + (size_t)i * DMODEL_;
        const float w0 = wr[tid];
        const float w1 = wr[tid + 256];
        const float w2 = wr[tid + 512];
        const float w3 = wr[tid + 768];
        #pragma unroll
        for (int r = 0; r < ROWS; ++r) {
            const float xi = xs[r][i];
            acc[r][0] = fmaf(xi, w0, acc[r][0]);
            acc[r][1] = fmaf(xi, w1, acc[r][1]);
            acc[r][2] = fmaf(xi, w2, acc[r][2]);
            acc[r][3] = fmaf(xi, w3, acc[r][3]);
        }
    }

    float bb[4], gg[4], be[4];
    #pragma unroll
    for (int c = 0; c < 4; ++c) {
        bb[c] = bias[tid + c * 256];
        gg[c] = gamma[tid + c * 256];
        be[c] = beta[tid + c * 256];
    }

    float y[ROWS][4];
    #pragma unroll
    for (int r = 0; r < ROWS; ++r) {
        const size_t rowoff = (size_t)(r0 + r) * DMODEL_;
        float s = 0.f, s2 = 0.f;
        #pragma unroll
        for (int c = 0; c < 4; ++c) {
            y[r][c] = acc[r][c] + bb[c] + Qres[rowoff + tid + c * 256];
            s  += y[r][c];
            s2 += y[r][c] * y[r][c];
        }
        #pragma unroll
        for (int m = 1; m < 64; m <<= 1) {
            s  += __shfl_xor(s,  m, 64);
            s2 += __shfl_xor(s2, m, 64);
        }
        if (lane == 0) part_s[r][wv] = make_float2(s, s2);
    }
    __syncthreads();

    #pragma unroll
    for (int r = 0; r < ROWS; ++r) {
        const size_t rowoff = (size_t)(r0 + r) * DMODEL_;
        const float2 p0 = part_s[r][0], p1 = part_s[r][1],
                     p2 = part_s[r][2], p3 = part_s[r][3];
        const float S  = p0.x + p1.x + p2.x + p3.x;
        const float S2 = p0.y + p1.y + p2.y + p3.y;
        const float mu   = S * (1.f / DMODEL_);
        const float var  = S2 * (1.f / DMODEL_) - mu * mu;
        const float rstd = rsqrtf(var + LN_EPS);
        #pragma unroll
        for (int c = 0; c < 4; ++c) {
            Out[rowoff + tid + c * 256] = (y[r][c] - mu) * rstd * gg[c] + be[c];
        }
    }
}

// ---------------------------------------------------------------------------
extern "C" void kernel_launch(void* const* d_in, const int* in_sizes, int n_in,
                              void* d_out, int out_size, void* d_ws, size_t ws_size,
                              hipStream_t stream)
{
    const float* q     = (const float*)d_in[0];
    const float* k     = (const float*)d_in[1];
    const float* v     = (const float*)d_in[2];
    const float* W_fc  = (const float*)d_in[3];
    const float* b_fc  = (const float*)d_in[4];
    const float* gamma = (const float*)d_in[5];
    const float* beta  = (const float*)d_in[6];

    char* ws = (char*)d_ws;
    short* qb   = (short*)(ws);               // 8 MB  [B,H,L,64] bf16 swizzled
    short* kb   = (short*)(ws + 8388608);     // 8 MB
    short* vb   = (short*)(ws + 16777216);    // 8 MB  [B,H,64,L] bf16 swizzled
    short* head = (short*)(ws + 25165824);    // 8 MB  [B,L,1024] bf16

    float* out  = (float*)d_out;
    float* attn = out + (size_t)B_ * L_ * DMODEL_;

    prep_qk<<<2048, 256, 0, stream>>>(q, qb);
    prep_qk<<<2048, 256, 0, stream>>>(k, kb);
    prep_v <<<2048, 256, 0, stream>>>(v, vb);

    dim3 g1(32, H_, B_);
    attn_mfma<<<g1, 256, 0, stream>>>(qb, kb, vb, attn, head);

    fc_ln_kernel<<<(B_ * L_) / ROWS, 256, 0, stream>>>(
        head, W_fc, b_fc, q, gamma, beta, out);
}

// Round 8
// 731.611 us; speedup vs baseline: 10.3658x; 1.3466x over previous
//
#include <hip/hip_runtime.h>
#include <hip/hip_bf16.h>
#include <math.h>

#define B_      2
#define L_      2048
#define H_      16
#define DMODEL_ 1024
#define LN_EPS  1e-5f

typedef __attribute__((ext_vector_type(8))) __bf16 bf16x8;
typedef __attribute__((ext_vector_type(8))) short  short8;
typedef __attribute__((ext_vector_type(4))) short  short4_t;
typedef __attribute__((ext_vector_type(4))) float  f32x4;

typedef const __attribute__((address_space(1))) void cgvoid_t;
typedef __attribute__((address_space(3))) void svoid_t;

__device__ __forceinline__ void gload16(const void* g, void* l) {
    __builtin_amdgcn_global_load_lds((cgvoid_t*)g, (svoid_t*)l, 16, 0, 0);
}
__device__ __forceinline__ short f2bf(float x) {
    __hip_bfloat16 h = __float2bfloat16(x);
    return __builtin_bit_cast(short, h);
}
__device__ __forceinline__ float bf2f(short s) {
    unsigned u = ((unsigned)(unsigned short)s) << 16;
    return __builtin_bit_cast(float, u);
}
__device__ __forceinline__ f32x4 mfma16(bf16x8 a, bf16x8 b, f32x4 c) {
    return __builtin_amdgcn_mfma_f32_16x16x32_bf16(a, b, c, 0, 0, 0);
}

// ---------------------------------------------------------------------------
// prep_qk: [B,L,H*64] f32 -> [B,H,L,64] bf16, 16B chunks XOR-swizzled within
// each 128B row (chunk c at position c ^ (l&7)).
// ---------------------------------------------------------------------------
__global__ __launch_bounds__(256) void prep_qk(const float* __restrict__ src,
                                               short* __restrict__ dst)
{
    const int t = blockIdx.x * 256 + threadIdx.x;
    const int c = t & 7, l = (t >> 3) & 2047, h = (t >> 14) & 15, b = t >> 18;
    const float* s = src + ((size_t)(b * L_ + l)) * DMODEL_ + h * 64 + c * 8;
    float4 f0 = *(const float4*)s;
    float4 f1 = *(const float4*)(s + 4);
    short8 o;
    o[0] = f2bf(f0.x); o[1] = f2bf(f0.y); o[2] = f2bf(f0.z); o[3] = f2bf(f0.w);
    o[4] = f2bf(f1.x); o[5] = f2bf(f1.y); o[6] = f2bf(f1.z); o[7] = f2bf(f1.w);
    short* d = dst + ((size_t)((b * H_ + h) * L_ + l)) * 64 + (c ^ (l & 7)) * 8;
    *(short8*)d = o;
}

// ---------------------------------------------------------------------------
// prep_v: [B,L,H*64] f32 -> [B,H,64,L] bf16 (transposed per head), chunk
// swizzle within each 64-k tile of each d-row.
// ---------------------------------------------------------------------------
__global__ __launch_bounds__(256) void prep_v(const float* __restrict__ src,
                                              short* __restrict__ dst)
{
    const int blk = blockIdx.x;
    const int g = blk & 63, h = (blk >> 6) & 15, b = blk >> 10;
    const int d = threadIdx.x & 63, lc = g * 4 + (threadIdx.x >> 6);
    const int l0 = lc * 8;
    const float* s = src + ((size_t)(b * L_ + l0)) * DMODEL_ + h * 64 + d;
    short8 o;
    #pragma unroll
    for (int j = 0; j < 8; ++j) o[j] = f2bf(s[(size_t)j * DMODEL_]);
    short* dp = dst + ((size_t)((b * H_ + h) * 64 + d)) * L_
              + (l0 & ~63) + (((lc & 7) ^ (d & 7)) * 8);
    *(short8*)dp = o;
}

// ---------------------------------------------------------------------------
// prep_w: W [k=1024][n=1024] f32 -> Wh = bf16(W^T), Wl = bf16(W^T - Wh),
// [n][k] layout, chunk-swizzled within each 64-k tile (chunk c at c^(n&7)).
// hi/lo split keeps fc's W at ~f32 precision through two MFMA accumulations.
// ---------------------------------------------------------------------------
__global__ __launch_bounds__(256) void prep_w(const float* __restrict__ W,
                                              short* __restrict__ Wh,
                                              short* __restrict__ Wl)
{
    const int t = blockIdx.x * 256 + threadIdx.x;   // 131072 threads
    const int n = t & 1023, kc = t >> 10;           // kc: 8-k chunk, 0..127
    short8 oh, ol;
    #pragma unroll
    for (int e = 0; e < 8; ++e) {
        float wv = W[(size_t)(kc * 8 + e) * 1024 + n];
        short hs = f2bf(wv);
        oh[e] = hs;
        ol[e] = f2bf(wv - bf2f(hs));
    }
    const size_t off = (size_t)n * 1024 + (kc >> 3) * 64 + (((kc & 7) ^ (n & 7)) * 8);
    *(short8*)(Wh + off) = oh;
    *(short8*)(Wl + off) = ol;
}

// ---------------------------------------------------------------------------
// attn_mfma (swapped QK^T: D = K.Q^T -> S^T tiles; lane owns one q row,
// 4 consecutive k per reg -> f32x4 attn stores, b64 P packs).
// Block = 64 q rows of one (b,h); 4 waves, wave w owns q rows w*16..+15.
// ---------------------------------------------------------------------------
__global__ __launch_bounds__(256) void attn_mfma(
    const short* __restrict__ Qb, const short* __restrict__ Kb,
    const short* __restrict__ Vb, float* __restrict__ attn,
    short* __restrict__ head)
{
    // XCD-aware swizzle (1024 blocks = 8 * 128, bijective): XCD x gets a
    // contiguous range of (bh, qt) -> K/V L2 locality per XCD (4 heads/XCD).
    const int bid = blockIdx.x;
    const int g = (bid & 7) * 128 + (bid >> 3);
    const int qt = g & 31, bh = g >> 5;
    const int h = bh & 15, b = bh >> 4;

    const int tid = threadIdx.x;
    const int lane = tid & 63, w = tid >> 6;
    const int kgrp = lane >> 4, l15 = lane & 15;
    const int q0 = qt * 64;

    __shared__ short qe_s[64 * 64];        // Q tile, later reused as P tile
    __shared__ short k2_s[2 * 64 * 64];    // K double buffer
    __shared__ short v2_s[2 * 64 * 64];    // V^T double buffer

    const char* Qg = (const char*)(Qb + ((size_t)bh * L_ + q0) * 64);
    const char* Kg = (const char*)(Kb + (size_t)bh * L_ * 64);
    const char* Vg = (const char*)(Vb + (size_t)bh * 64 * L_);

    gload16(Qg + (w * 64 + lane) * 16, (char*)qe_s + w * 1024 + lane * 16);
    gload16(Qg + 4096 + (w * 64 + lane) * 16,
            (char*)qe_s + 4096 + w * 1024 + lane * 16);
    __syncthreads();

    const int prow = w * 16 + l15;         // this lane's q row (block-local)
    bf16x8 bq0 = *(const bf16x8*)((const char*)qe_s + prow * 128 + ((kgrp ^ (prow & 7)) * 16));
    bf16x8 bq1 = *(const bf16x8*)((const char*)qe_s + prow * 128 + (((kgrp + 4) ^ (prow & 7)) * 16));
    __syncthreads();

    auto stageK = [&](int kt, int bu) {
        const char* kg = Kg + (size_t)kt * 8192;
        char* lk = (char*)k2_s + bu * 8192;
        gload16(kg + (w * 64 + lane) * 16, lk + w * 1024 + lane * 16);
        gload16(kg + 4096 + (w * 64 + lane) * 16, lk + 4096 + w * 1024 + lane * 16);
    };
    auto stageV = [&](int kt, int bu) {
        const char* vg = Vg + (size_t)kt * 128;
        char* lv = (char*)v2_s + bu * 8192;
        int cid = w * 64 + lane;
        gload16(vg + (size_t)(cid >> 3) * 4096 + (cid & 7) * 16, lv + w * 1024 + lane * 16);
        cid += 256;
        gload16(vg + (size_t)(cid >> 3) * 4096 + (cid & 7) * 16, lv + 4096 + w * 1024 + lane * 16);
    };

    // ---------------- pass 1: row sums ----------------
    float rsum = 0.f;
    stageK(0, 0);
    __syncthreads();
    int buf = 0;
    for (int kt = 0; kt < 32; ++kt) {
        if (kt < 31) stageK(kt + 1, buf ^ 1);
        const char* ks = (const char*)k2_s + buf * 8192;
        #pragma unroll
        for (int t = 0; t < 4; ++t) {
            const int brow = t * 16 + l15;
            f32x4 acc = {0.f, 0.f, 0.f, 0.f};
            bf16x8 k0 = *(const bf16x8*)(ks + brow * 128 + ((kgrp ^ (brow & 7)) * 16));
            bf16x8 k1 = *(const bf16x8*)(ks + brow * 128 + (((kgrp + 4) ^ (brow & 7)) * 16));
            acc = mfma16(k0, bq0, acc);
            acc = mfma16(k1, bq1, acc);
            #pragma unroll
            for (int r = 0; r < 4; ++r) rsum += __expf(acc[r] * 0.125f);
        }
        __syncthreads();
        buf ^= 1;
    }
    rsum += __shfl_xor(rsum, 16, 64);
    rsum += __shfl_xor(rsum, 32, 64);
    const float rinv = 1.0f / rsum;

    // ---------------- pass 2: attn write + PV ----------------
    f32x4 oacc[4];
    #pragma unroll
    for (int t = 0; t < 4; ++t) oacc[t] = (f32x4){0.f, 0.f, 0.f, 0.f};

    float* arow_p = attn + ((size_t)bh * L_ + q0 + prow) * L_;
    char* pbase = (char*)qe_s + prow * 128;
    const int pswz0 = (kgrp ^ (prow & 7)) * 16;
    const int pswz1 = ((kgrp + 4) ^ (prow & 7)) * 16;

    stageK(0, 0);
    stageV(0, 0);
    __syncthreads();
    buf = 0;
    for (int kt = 0; kt < 32; ++kt) {
        if (kt < 31) { stageK(kt + 1, buf ^ 1); stageV(kt + 1, buf ^ 1); }
        const char* ks = (const char*)k2_s + buf * 8192;
        const char* vs = (const char*)v2_s + buf * 8192;
        #pragma unroll
        for (int t = 0; t < 4; ++t) {
            const int brow = t * 16 + l15;
            f32x4 acc = {0.f, 0.f, 0.f, 0.f};
            bf16x8 k0 = *(const bf16x8*)(ks + brow * 128 + ((kgrp ^ (brow & 7)) * 16));
            bf16x8 k1 = *(const bf16x8*)(ks + brow * 128 + (((kgrp + 4) ^ (brow & 7)) * 16));
            acc = mfma16(k0, bq0, acc);
            acc = mfma16(k1, bq1, acc);
            // lane holds S^T: q = prow, k = kt*64 + t*16 + kgrp*4 + r
            f32x4 ev;
            ev[0] = __expf(acc[0] * 0.125f) * rinv;
            ev[1] = __expf(acc[1] * 0.125f) * rinv;
            ev[2] = __expf(acc[2] * 0.125f) * rinv;
            ev[3] = __expf(acc[3] * 0.125f) * rinv;
            __builtin_nontemporal_store(ev,
                (f32x4*)(arow_p + kt * 64 + t * 16 + kgrp * 4));
            short4_t pk;
            pk[0] = f2bf(ev[0]); pk[1] = f2bf(ev[1]);
            pk[2] = f2bf(ev[2]); pk[3] = f2bf(ev[3]);
            const int pc = (t * 2 + (kgrp >> 1)) ^ (prow & 7);
            *(short4_t*)((char*)qe_s + prow * 128 + pc * 16 + (kgrp & 1) * 8) = pk;
        }
        // PV (P tile rows are wave-private: no barrier needed before reads)
        bf16x8 pa0 = *(const bf16x8*)(pbase + pswz0);
        bf16x8 pa1 = *(const bf16x8*)(pbase + pswz1);
        #pragma unroll
        for (int t = 0; t < 4; ++t) {
            const int brow = t * 16 + l15;   // d index
            bf16x8 v0 = *(const bf16x8*)(vs + brow * 128 + ((kgrp ^ (brow & 7)) * 16));
            bf16x8 v1 = *(const bf16x8*)(vs + brow * 128 + (((kgrp + 4) ^ (brow & 7)) * 16));
            oacc[t] = mfma16(pa0, v0, oacc[t]);
            oacc[t] = mfma16(pa1, v1, oacc[t]);
        }
        __syncthreads();
        buf ^= 1;
    }

    // head epilogue: D col = d (t*16+l15), row = q (kgrp*4+r); write into
    // fc's swizzled X layout.
    #pragma unroll
    for (int t = 0; t < 4; ++t) {
        #pragma unroll
        for (int r = 0; r < 4; ++r) {
            const int rowidx = b * L_ + q0 + w * 16 + kgrp * 4 + r;
            const int dl = t * 16 + l15;
            head[(size_t)rowidx * 1024 + h * 64
                 + (((dl >> 3) ^ (rowidx & 7)) * 8) + (dl & 7)] = f2bf(oacc[t][r]);
        }
    }
}

// ---------------------------------------------------------------------------
// fc_mfma: Y = X @ W + bias + residual.  X = head [4096][1024] bf16 swz,
// Wh/Wl = W^T hi/lo bf16 swz.  Block = 64 tok x 64 n, 4 waves.
// Swapped operands: D col = tok, row = n -> float4 stores.
// ---------------------------------------------------------------------------
__global__ __launch_bounds__(256) void fc_mfma(
    const short* __restrict__ Xs, const short* __restrict__ Wh,
    const short* __restrict__ Wl, const float* __restrict__ bias,
    const float* __restrict__ Qres, float* __restrict__ Y)
{
    const int n0 = blockIdx.x * 64, tok0 = blockIdx.y * 64;
    const int tid = threadIdx.x;
    const int lane = tid & 63, w = tid >> 6;
    const int kgrp = lane >> 4, l15 = lane & 15;

    __shared__ short x2_s[2 * 64 * 64];
    __shared__ short wh2_s[2 * 64 * 64];
    __shared__ short wl2_s[2 * 64 * 64];

    auto stageX = [&](int kt, int bu) {
        const char* xg = (const char*)Xs + (size_t)tok0 * 2048 + kt * 128;
        char* lx = (char*)x2_s + bu * 8192;
        int cid = w * 64 + lane;
        gload16(xg + (size_t)(cid >> 3) * 2048 + (cid & 7) * 16, lx + w * 1024 + lane * 16);
        cid += 256;
        gload16(xg + (size_t)(cid >> 3) * 2048 + (cid & 7) * 16, lx + 4096 + w * 1024 + lane * 16);
    };
    auto stageW = [&](int kt, int bu) {
        const char* wgh = (const char*)Wh + (size_t)n0 * 2048 + kt * 128;
        const char* wgl = (const char*)Wl + (size_t)n0 * 2048 + kt * 128;
        char* lh = (char*)wh2_s + bu * 8192;
        char* ll = (char*)wl2_s + bu * 8192;
        int cid = w * 64 + lane;
        const int ldst = w * 1024 + lane * 16;
        size_t go = (size_t)(cid >> 3) * 2048 + (cid & 7) * 16;
        gload16(wgh + go, lh + ldst);
        gload16(wgl + go, ll + ldst);
        cid += 256;
        go = (size_t)(cid >> 3) * 2048 + (cid & 7) * 16;
        gload16(wgh + go, lh + 4096 + ldst);
        gload16(wgl + go, ll + 4096 + ldst);
    };

    f32x4 oacc[4];
    #pragma unroll
    for (int t = 0; t < 4; ++t) oacc[t] = (f32x4){0.f, 0.f, 0.f, 0.f};

    stageX(0, 0);
    stageW(0, 0);
    __syncthreads();
    int buf = 0;
    const int xrow = w * 16 + l15;       // tok row for B-frag
    for (int kt = 0; kt < 16; ++kt) {
        if (kt < 15) { stageX(kt + 1, buf ^ 1); stageW(kt + 1, buf ^ 1); }
        const char* xs = (const char*)x2_s + buf * 8192;
        const char* wh = (const char*)wh2_s + buf * 8192;
        const char* wl = (const char*)wl2_s + buf * 8192;
        bf16x8 bx0 = *(const bf16x8*)(xs + xrow * 128 + ((kgrp ^ (xrow & 7)) * 16));
        bf16x8 bx1 = *(const bf16x8*)(xs + xrow * 128 + (((kgrp + 4) ^ (xrow & 7)) * 16));
        #pragma unroll
        for (int nt = 0; nt < 4; ++nt) {
            const int wrow = nt * 16 + l15;
            const int s0 = wrow * 128 + ((kgrp ^ (wrow & 7)) * 16);
            const int s1 = wrow * 128 + (((kgrp + 4) ^ (wrow & 7)) * 16);
            oacc[nt] = mfma16(*(const bf16x8*)(wh + s0), bx0, oacc[nt]);
            oacc[nt] = mfma16(*(const bf16x8*)(wh + s1), bx1, oacc[nt]);
            oacc[nt] = mfma16(*(const bf16x8*)(wl + s0), bx0, oacc[nt]);
            oacc[nt] = mfma16(*(const bf16x8*)(wl + s1), bx1, oacc[nt]);
        }
        __syncthreads();
        buf ^= 1;
    }

    const int tok = tok0 + w * 16 + l15;
    #pragma unroll
    for (int nt = 0; nt < 4; ++nt) {
        const int n = n0 + nt * 16 + kgrp * 4;
        float4 bb = *(const float4*)(bias + n);
        float4 qq = *(const float4*)(Qres + (size_t)tok * DMODEL_ + n);
        float4 yy;
        yy.x = oacc[nt][0] + bb.x + qq.x;
        yy.y = oacc[nt][1] + bb.y + qq.y;
        yy.z = oacc[nt][2] + bb.z + qq.z;
        yy.w = oacc[nt][3] + bb.w + qq.w;
        *(float4*)(Y + (size_t)tok * DMODEL_ + n) = yy;
    }
}

// ---------------------------------------------------------------------------
// ln_kernel: Out = (Y - mu)*rstd*gamma + beta, one wave per token row.
// ---------------------------------------------------------------------------
__global__ __launch_bounds__(256) void ln_kernel(
    const float* __restrict__ Y, const float* __restrict__ gamma,
    const float* __restrict__ beta, float* __restrict__ Out)
{
    const int tok = blockIdx.x * 4 + (threadIdx.x >> 6);
    const int lane = threadIdx.x & 63;
    const float4* yp = (const float4*)(Y + (size_t)tok * DMODEL_);
    float4 vv[4];
    float s = 0.f, s2 = 0.f;
    #pragma unroll
    for (int i = 0; i < 4; ++i) {
        vv[i] = yp[i * 64 + lane];
        s  += vv[i].x + vv[i].y + vv[i].z + vv[i].w;
        s2 += vv[i].x * vv[i].x + vv[i].y * vv[i].y
            + vv[i].z * vv[i].z + vv[i].w * vv[i].w;
    }
    #pragma unroll
    for (int m = 1; m < 64; m <<= 1) {
        s  += __shfl_xor(s,  m, 64);
        s2 += __shfl_xor(s2, m, 64);
    }
    const float mu   = s * (1.f / DMODEL_);
    const float var  = s2 * (1.f / DMODEL_) - mu * mu;
    const float rstd = rsqrtf(var + LN_EPS);
    const float4* g4 = (const float4*)gamma;
    const float4* b4 = (const float4*)beta;
    float4* op = (float4*)(Out + (size_t)tok * DMODEL_);
    #pragma unroll
    for (int i = 0; i < 4; ++i) {
        const int idx = i * 64 + lane;
        float4 g = g4[idx], be = b4[idx], o;
        o.x = (vv[i].x - mu) * rstd * g.x + be.x;
        o.y = (vv[i].y - mu) * rstd * g.y + be.y;
        o.z = (vv[i].z - mu) * rstd * g.z + be.z;
        o.w = (vv[i].w - mu) * rstd * g.w + be.w;
        op[idx] = o;
    }
}

// ---------------------------------------------------------------------------
extern "C" void kernel_launch(void* const* d_in, const int* in_sizes, int n_in,
                              void* d_out, int out_size, void* d_ws, size_t ws_size,
                              hipStream_t stream)
{
    const float* q     = (const float*)d_in[0];
    const float* k     = (const float*)d_in[1];
    const float* v     = (const float*)d_in[2];
    const float* W_fc  = (const float*)d_in[3];
    const float* b_fc  = (const float*)d_in[4];
    const float* gamma = (const float*)d_in[5];
    const float* beta  = (const float*)d_in[6];

    char* ws = (char*)d_ws;
    short* qb   = (short*)(ws);               // 8 MB  [B,H,L,64] bf16 swz
    short* kb   = (short*)(ws + 8388608);     // 8 MB
    short* vb   = (short*)(ws + 16777216);    // 8 MB  [B,H,64,L] bf16 swz
    short* head = (short*)(ws + 25165824);    // 8 MB  [B*L,1024] bf16 swz
    short* whi  = (short*)(ws + 33554432);    // 2 MB  W^T hi bf16 swz
    short* wlo  = (short*)(ws + 35651584);    // 2 MB  W^T lo bf16 swz
    float* y    = (float*)(ws + 37748736);    // 16 MB fc output (pre-LN)

    float* out  = (float*)d_out;
    float* attn = out + (size_t)B_ * L_ * DMODEL_;

    prep_qk<<<2048, 256, 0, stream>>>(q, qb);
    prep_qk<<<2048, 256, 0, stream>>>(k, kb);
    prep_v <<<2048, 256, 0, stream>>>(v, vb);
    prep_w <<<512,  256, 0, stream>>>(W_fc, whi, wlo);

    attn_mfma<<<1024, 256, 0, stream>>>(qb, kb, vb, attn, head);

    fc_mfma<<<dim3(16, 64), 256, 0, stream>>>(head, whi, wlo, b_fc, q, y);

    ln_kernel<<<1024, 256, 0, stream>>>(y, gamma, beta, out);
}

// Round 12
// 725.029 us; speedup vs baseline: 10.4599x; 1.0091x over previous
//
#include <hip/hip_runtime.h>
#include <hip/hip_bf16.h>
#include <math.h>

#define B_      2
#define L_      2048
#define H_      16
#define DMODEL_ 1024
#define LN_EPS  1e-5f

typedef __attribute__((ext_vector_type(8))) __bf16 bf16x8;
typedef __attribute__((ext_vector_type(8))) short  short8;
typedef __attribute__((ext_vector_type(4))) short  short4_t;
typedef __attribute__((ext_vector_type(4))) float  f32x4;

typedef const __attribute__((address_space(1))) void cgvoid_t;
typedef __attribute__((address_space(3))) void svoid_t;

__device__ __forceinline__ void gload16(const void* g, void* l) {
    __builtin_amdgcn_global_load_lds((cgvoid_t*)g, (svoid_t*)l, 16, 0, 0);
}
__device__ __forceinline__ short f2bf(float x) {
    __hip_bfloat16 h = __float2bfloat16(x);
    return __builtin_bit_cast(short, h);
}
__device__ __forceinline__ float bf2f(short s) {
    unsigned u = ((unsigned)(unsigned short)s) << 16;
    return __builtin_bit_cast(float, u);
}
__device__ __forceinline__ f32x4 mfma16(bf16x8 a, bf16x8 b, f32x4 c) {
    return __builtin_amdgcn_mfma_f32_16x16x32_bf16(a, b, c, 0, 0, 0);
}

// ---------------------------------------------------------------------------
// prep_qk: [B,L,H*64] f32 -> [B,H,L,64] bf16, 16B chunks XOR-swizzled within
// each 128B row (chunk c at position c ^ (l&7)).
// ---------------------------------------------------------------------------
__global__ __launch_bounds__(256) void prep_qk(const float* __restrict__ src,
                                               short* __restrict__ dst)
{
    const int t = blockIdx.x * 256 + threadIdx.x;
    const int c = t & 7, l = (t >> 3) & 2047, h = (t >> 14) & 15, b = t >> 18;
    const float* s = src + ((size_t)(b * L_ + l)) * DMODEL_ + h * 64 + c * 8;
    float4 f0 = *(const float4*)s;
    float4 f1 = *(const float4*)(s + 4);
    short8 o;
    o[0] = f2bf(f0.x); o[1] = f2bf(f0.y); o[2] = f2bf(f0.z); o[3] = f2bf(f0.w);
    o[4] = f2bf(f1.x); o[5] = f2bf(f1.y); o[6] = f2bf(f1.z); o[7] = f2bf(f1.w);
    short* d = dst + ((size_t)((b * H_ + h) * L_ + l)) * 64 + (c ^ (l & 7)) * 8;
    *(short8*)d = o;
}

// ---------------------------------------------------------------------------
// prep_v: [B,L,H*64] f32 -> [B,H,64,L] bf16 (transposed per head) via LDS
// transpose tile: coalesced 64B reads AND writes. Chunk swizzle within each
// 64-k tile of each d-row (chunk c at c ^ (d&7)).
// ---------------------------------------------------------------------------
__global__ __launch_bounds__(256) void prep_v(const float* __restrict__ src,
                                              short* __restrict__ dst)
{
    const int blk = blockIdx.x;                 // (b*16+h)*32 + lt
    const int lt = blk & 31, h = (blk >> 5) & 15, b = blk >> 9;
    const int l0 = lt * 64;
    const int t = threadIdx.x;

    __shared__ float tile[64][65];

    {   // load 64 l x 64 d f32 tile, 4 threads/row x 64B
        const int row = t >> 2, seg = t & 3;
        const float4* s = (const float4*)(src
            + ((size_t)(b * L_ + l0 + row)) * DMODEL_ + h * 64 + seg * 16);
        #pragma unroll
        for (int i = 0; i < 4; ++i) {
            float4 v = s[i];
            tile[row][seg * 16 + i * 4 + 0] = v.x;
            tile[row][seg * 16 + i * 4 + 1] = v.y;
            tile[row][seg * 16 + i * 4 + 2] = v.z;
            tile[row][seg * 16 + i * 4 + 3] = v.w;
        }
    }
    __syncthreads();

    const int d = t >> 2, p = t & 3;
    short* drow = dst + ((size_t)((b * H_ + h) * 64 + d)) * L_ + l0;
    #pragma unroll
    for (int cc = 0; cc < 2; ++cc) {
        const int c = p + cc * 4;               // chunk 0..7 (8 l each)
        short8 o;
        #pragma unroll
        for (int j = 0; j < 8; ++j) o[j] = f2bf(tile[c * 8 + j][d]);
        *(short8*)(drow + ((c ^ (d & 7)) * 8)) = o;
    }
}

// ---------------------------------------------------------------------------
// prep_w: W [k=1024][n=1024] f32 -> Wh = bf16(W^T), Wl = bf16(W^T - Wh),
// [n][k] layout, chunk-swizzled within each 64-k tile (chunk c at c^(n&7)).
// hi/lo split keeps fc's W at ~f32 precision through two MFMA accumulations.
// ---------------------------------------------------------------------------
__global__ __launch_bounds__(256) void prep_w(const float* __restrict__ W,
                                              short* __restrict__ Wh,
                                              short* __restrict__ Wl)
{
    const int t = blockIdx.x * 256 + threadIdx.x;   // 131072 threads
    const int n = t & 1023, kc = t >> 10;           // kc: 8-k chunk, 0..127
    short8 oh, ol;
    #pragma unroll
    for (int e = 0; e < 8; ++e) {
        float wv = W[(size_t)(kc * 8 + e) * 1024 + n];
        short hs = f2bf(wv);
        oh[e] = hs;
        ol[e] = f2bf(wv - bf2f(hs));
    }
    const size_t off = (size_t)n * 1024 + (kc >> 3) * 64 + (((kc & 7) ^ (n & 7)) * 8);
    *(short8*)(Wh + off) = oh;
    *(short8*)(Wl + off) = ol;
}

// ---------------------------------------------------------------------------
// attn_mfma (swapped QK^T: D = K.Q^T -> S^T tiles; lane owns one q row,
// 4 consecutive k per reg -> f32x4 attn stores, b64 P packs).
// Block = 128 q rows of one (b,h); 8 waves, wave w owns q rows w*16..+15.
// K/V staged once per 128 rows (was 64): staging traffic halved, 2x MFMA
// per barrier.
// ---------------------------------------------------------------------------
__global__ __launch_bounds__(512) void attn_mfma(
    const short* __restrict__ Qb, const short* __restrict__ Kb,
    const short* __restrict__ Vb, float* __restrict__ attn,
    short* __restrict__ head)
{
    // XCD-aware swizzle (512 blocks = 8 * 64, bijective).
    const int bid = blockIdx.x;
    const int g = (bid & 7) * 64 + (bid >> 3);
    const int qt = g & 15, bh = g >> 4;
    const int h = bh & 15, b = bh >> 4;

    const int tid = threadIdx.x;
    const int lane = tid & 63, w = tid >> 6;
    const int kgrp = lane >> 4, l15 = lane & 15;
    const int q0 = qt * 128;

    __shared__ short qe_s[128 * 64];       // Q tile (16KB), later P tile
    __shared__ short k2_s[2 * 64 * 64];    // K double buffer (16KB)
    __shared__ short v2_s[2 * 64 * 64];    // V^T double buffer (16KB)

    const char* Qg = (const char*)(Qb + ((size_t)bh * L_ + q0) * 64);
    const char* Kg = (const char*)(Kb + (size_t)bh * L_ * 64);
    const char* Vg = (const char*)(Vb + (size_t)bh * 64 * L_);

    // stage Q tile (16KB linear, 512 threads x 2 x 16B)
    gload16(Qg + tid * 16, (char*)qe_s + tid * 16);
    gload16(Qg + 8192 + tid * 16, (char*)qe_s + 8192 + tid * 16);
    __syncthreads();

    const int prow = w * 16 + l15;         // this lane's q row (block-local)
    bf16x8 bq0 = *(const bf16x8*)((const char*)qe_s + prow * 128 + ((kgrp ^ (prow & 7)) * 16));
    bf16x8 bq1 = *(const bf16x8*)((const char*)qe_s + prow * 128 + (((kgrp + 4) ^ (prow & 7)) * 16));
    __syncthreads();

    auto stageK = [&](int kt, int bu) {
        gload16(Kg + (size_t)kt * 8192 + tid * 16,
                (char*)k2_s + bu * 8192 + tid * 16);
    };
    auto stageV = [&](int kt, int bu) {
        gload16(Vg + (size_t)kt * 128 + (size_t)(tid >> 3) * 4096 + (tid & 7) * 16,
                (char*)v2_s + bu * 8192 + tid * 16);
    };

    // ---------------- pass 1: row sums ----------------
    float rsum = 0.f;
    stageK(0, 0);
    __syncthreads();
    int buf = 0;
    for (int kt = 0; kt < 32; ++kt) {
        if (kt < 31) stageK(kt + 1, buf ^ 1);
        const char* ks = (const char*)k2_s + buf * 8192;
        #pragma unroll
        for (int t = 0; t < 4; ++t) {
            const int brow = t * 16 + l15;
            f32x4 acc = {0.f, 0.f, 0.f, 0.f};
            bf16x8 k0 = *(const bf16x8*)(ks + brow * 128 + ((kgrp ^ (brow & 7)) * 16));
            bf16x8 k1 = *(const bf16x8*)(ks + brow * 128 + (((kgrp + 4) ^ (brow & 7)) * 16));
            acc = mfma16(k0, bq0, acc);
            acc = mfma16(k1, bq1, acc);
            #pragma unroll
            for (int r = 0; r < 4; ++r) rsum += __expf(acc[r] * 0.125f);
        }
        __syncthreads();
        buf ^= 1;
    }
    rsum += __shfl_xor(rsum, 16, 64);
    rsum += __shfl_xor(rsum, 32, 64);
    const float rinv = 1.0f / rsum;

    // ---------------- pass 2: attn write + PV ----------------
    f32x4 oacc[4];
    #pragma unroll
    for (int t = 0; t < 4; ++t) oacc[t] = (f32x4){0.f, 0.f, 0.f, 0.f};

    float* arow_p = attn + ((size_t)bh * L_ + q0 + prow) * L_;
    char* pbase = (char*)qe_s + prow * 128;
    const int pswz0 = (kgrp ^ (prow & 7)) * 16;
    const int pswz1 = ((kgrp + 4) ^ (prow & 7)) * 16;

    stageK(0, 0);
    stageV(0, 0);
    __syncthreads();
    buf = 0;
    for (int kt = 0; kt < 32; ++kt) {
        if (kt < 31) { stageK(kt + 1, buf ^ 1); stageV(kt + 1, buf ^ 1); }
        const char* ks = (const char*)k2_s + buf * 8192;
        const char* vs = (const char*)v2_s + buf * 8192;
        #pragma unroll
        for (int t = 0; t < 4; ++t) {
            const int brow = t * 16 + l15;
            f32x4 acc = {0.f, 0.f, 0.f, 0.f};
            bf16x8 k0 = *(const bf16x8*)(ks + brow * 128 + ((kgrp ^ (brow & 7)) * 16));
            bf16x8 k1 = *(const bf16x8*)(ks + brow * 128 + (((kgrp + 4) ^ (brow & 7)) * 16));
            acc = mfma16(k0, bq0, acc);
            acc = mfma16(k1, bq1, acc);
            // lane holds S^T: q = prow, k = kt*64 + t*16 + kgrp*4 + r
            f32x4 ev;
            ev[0] = __expf(acc[0] * 0.125f) * rinv;
            ev[1] = __expf(acc[1] * 0.125f) * rinv;
            ev[2] = __expf(acc[2] * 0.125f) * rinv;
            ev[3] = __expf(acc[3] * 0.125f) * rinv;
            __builtin_nontemporal_store(ev,
                (f32x4*)(arow_p + kt * 64 + t * 16 + kgrp * 4));
            short4_t pk;
            pk[0] = f2bf(ev[0]); pk[1] = f2bf(ev[1]);
            pk[2] = f2bf(ev[2]); pk[3] = f2bf(ev[3]);
            const int pc = (t * 2 + (kgrp >> 1)) ^ (prow & 7);
            *(short4_t*)((char*)qe_s + prow * 128 + pc * 16 + (kgrp & 1) * 8) = pk;
        }
        // PV (P tile rows are wave-private: no barrier needed before reads)
        bf16x8 pa0 = *(const bf16x8*)(pbase + pswz0);
        bf16x8 pa1 = *(const bf16x8*)(pbase + pswz1);
        __builtin_amdgcn_s_setprio(1);
        #pragma unroll
        for (int t = 0; t < 4; ++t) {
            const int brow = t * 16 + l15;   // d index
            bf16x8 v0 = *(const bf16x8*)(vs + brow * 128 + ((kgrp ^ (brow & 7)) * 16));
            bf16x8 v1 = *(const bf16x8*)(vs + brow * 128 + (((kgrp + 4) ^ (brow & 7)) * 16));
            oacc[t] = mfma16(pa0, v0, oacc[t]);
            oacc[t] = mfma16(pa1, v1, oacc[t]);
        }
        __builtin_amdgcn_s_setprio(0);
        __syncthreads();
        buf ^= 1;
    }

    // head epilogue: D col = d (t*16+l15), row = q (kgrp*4+r); write into
    // fc's swizzled X layout.
    #pragma unroll
    for (int t = 0; t < 4; ++t) {
        #pragma unroll
        for (int r = 0; r < 4; ++r) {
            const int rowidx = b * L_ + q0 + w * 16 + kgrp * 4 + r;
            const int dl = t * 16 + l15;
            head[(size_t)rowidx * 1024 + h * 64
                 + (((dl >> 3) ^ (rowidx & 7)) * 8) + (dl & 7)] = f2bf(oacc[t][r]);
        }
    }
}

// ---------------------------------------------------------------------------
// fc_mfma: Y = X @ W + bias + residual.  X = head [4096][1024] bf16 swz,
// Wh/Wl = W^T hi/lo bf16 swz.  Block = 128 tok x 64 n, 8 waves.
// Swapped operands: D col = tok, row = n -> float4 stores.
// ---------------------------------------------------------------------------
__global__ __launch_bounds__(512) void fc_mfma(
    const short* __restrict__ Xs, const short* __restrict__ Wh,
    const short* __restrict__ Wl, const float* __restrict__ bias,
    const float* __restrict__ Qres, float* __restrict__ Y)
{
    const int n0 = blockIdx.x * 64, tok0 = blockIdx.y * 128;
    const int tid = threadIdx.x;
    const int lane = tid & 63, w = tid >> 6;
    const int kgrp = lane >> 4, l15 = lane & 15;

    __shared__ short x2_s[2 * 128 * 64];   // 32KB dbuf
    __shared__ short wh2_s[2 * 64 * 64];   // 16KB
    __shared__ short wl2_s[2 * 64 * 64];   // 16KB

    auto stageX = [&](int kt, int bu) {
        const char* xg = (const char*)Xs + (size_t)tok0 * 2048 + kt * 128;
        char* lx = (char*)x2_s + bu * 16384;
        gload16(xg + (size_t)(tid >> 3) * 2048 + (tid & 7) * 16, lx + tid * 16);
        const int cid = tid + 512;
        gload16(xg + (size_t)(cid >> 3) * 2048 + (cid & 7) * 16, lx + 8192 + tid * 16);
    };
    auto stageW = [&](int kt, int bu) {
        const size_t go = (size_t)n0 * 2048 + kt * 128
                        + (size_t)(tid >> 3) * 2048 + (tid & 7) * 16;
        gload16((const char*)Wh + go, (char*)wh2_s + bu * 8192 + tid * 16);
        gload16((const char*)Wl + go, (char*)wl2_s + bu * 8192 + tid * 16);
    };

    f32x4 oacc[4];
    #pragma unroll
    for (int t = 0; t < 4; ++t) oacc[t] = (f32x4){0.f, 0.f, 0.f, 0.f};

    stageX(0, 0);
    stageW(0, 0);
    __syncthreads();
    int buf = 0;
    const int xrow = w * 16 + l15;       // tok row for B-frag (0..127)
    for (int kt = 0; kt < 16; ++kt) {
        if (kt < 15) { stageX(kt + 1, buf ^ 1); stageW(kt + 1, buf ^ 1); }
        const char* xs = (const char*)x2_s + buf * 16384;
        const char* wh = (const char*)wh2_s + buf * 8192;
        const char* wl = (const char*)wl2_s + buf * 8192;
        bf16x8 bx0 = *(const bf16x8*)(xs + xrow * 128 + ((kgrp ^ (xrow & 7)) * 16));
        bf16x8 bx1 = *(const bf16x8*)(xs + xrow * 128 + (((kgrp + 4) ^ (xrow & 7)) * 16));
        __builtin_amdgcn_s_setprio(1);
        #pragma unroll
        for (int nt = 0; nt < 4; ++nt) {
            const int wrow = nt * 16 + l15;
            const int s0 = wrow * 128 + ((kgrp ^ (wrow & 7)) * 16);
            const int s1 = wrow * 128 + (((kgrp + 4) ^ (wrow & 7)) * 16);
            oacc[nt] = mfma16(*(const bf16x8*)(wh + s0), bx0, oacc[nt]);
            oacc[nt] = mfma16(*(const bf16x8*)(wh + s1), bx1, oacc[nt]);
            oacc[nt] = mfma16(*(const bf16x8*)(wl + s0), bx0, oacc[nt]);
            oacc[nt] = mfma16(*(const bf16x8*)(wl + s1), bx1, oacc[nt]);
        }
        __builtin_amdgcn_s_setprio(0);
        __syncthreads();
        buf ^= 1;
    }

    const int tok = tok0 + w * 16 + l15;
    #pragma unroll
    for (int nt = 0; nt < 4; ++nt) {
        const int n = n0 + nt * 16 + kgrp * 4;
        float4 bb = *(const float4*)(bias + n);
        float4 qq = *(const float4*)(Qres + (size_t)tok * DMODEL_ + n);
        float4 yy;
        yy.x = oacc[nt][0] + bb.x + qq.x;
        yy.y = oacc[nt][1] + bb.y + qq.y;
        yy.z = oacc[nt][2] + bb.z + qq.z;
        yy.w = oacc[nt][3] + bb.w + qq.w;
        *(float4*)(Y + (size_t)tok * DMODEL_ + n) = yy;
    }
}

// ---------------------------------------------------------------------------
// ln_kernel: Out = (Y - mu)*rstd*gamma + beta, one wave per token row.
// ---------------------------------------------------------------------------
__global__ __launch_bounds__(256) void ln_kernel(
    const float* __restrict__ Y, const float* __restrict__ gamma,
    const float* __restrict__ beta, float* __restrict__ Out)
{
    const int tok = blockIdx.x * 4 + (threadIdx.x >> 6);
    const int lane = threadIdx.x & 63;
    const float4* yp = (const float4*)(Y + (size_t)tok * DMODEL_);
    float4 vv[4];
    float s = 0.f, s2 = 0.f;
    #pragma unroll
    for (int i = 0; i < 4; ++i) {
        vv[i] = yp[i * 64 + lane];
        s  += vv[i].x + vv[i].y + vv[i].z + vv[i].w;
        s2 += vv[i].x * vv[i].x + vv[i].y * vv[i].y
            + vv[i].z * vv[i].z + vv[i].w * vv[i].w;
    }
    #pragma unroll
    for (int m = 1; m < 64; m <<= 1) {
        s  += __shfl_xor(s,  m, 64);
        s2 += __shfl_xor(s2, m, 64);
    }
    const float mu   = s * (1.f / DMODEL_);
    const float var  = s2 * (1.f / DMODEL_) - mu * mu;
    const float rstd = rsqrtf(var + LN_EPS);
    const float4* g4 = (const float4*)gamma;
    const float4* b4 = (const float4*)beta;
    float4* op = (float4*)(Out + (size_t)tok * DMODEL_);
    #pragma unroll
    for (int i = 0; i < 4; ++i) {
        const int idx = i * 64 + lane;
        float4 g = g4[idx], be = b4[idx], o;
        o.x = (vv[i].x - mu) * rstd * g.x + be.x;
        o.y = (vv[i].y - mu) * rstd * g.y + be.y;
        o.z = (vv[i].z - mu) * rstd * g.z + be.z;
        o.w = (vv[i].w - mu) * rstd * g.w + be.w;
        op[idx] = o;
    }
}

// ---------------------------------------------------------------------------
extern "C" void kernel_launch(void* const* d_in, const int* in_sizes, int n_in,
                              void* d_out, int out_size, void* d_ws, size_t ws_size,
                              hipStream_t stream)
{
    const float* q     = (const float*)d_in[0];
    const float* k     = (const float*)d_in[1];
    const float* v     = (const float*)d_in[2];
    const float* W_fc  = (const float*)d_in[3];
    const float* b_fc  = (const float*)d_in[4];
    const float* gamma = (const float*)d_in[5];
    const float* beta  = (const float*)d_in[6];

    char* ws = (char*)d_ws;
    short* qb   = (short*)(ws);               // 8 MB  [B,H,L,64] bf16 swz
    short* kb   = (short*)(ws + 8388608);     // 8 MB
    short* vb   = (short*)(ws + 16777216);    // 8 MB  [B,H,64,L] bf16 swz
    short* head = (short*)(ws + 25165824);    // 8 MB  [B*L,1024] bf16 swz
    short* whi  = (short*)(ws + 33554432);    // 2 MB  W^T hi bf16 swz
    short* wlo  = (short*)(ws + 35651584);    // 2 MB  W^T lo bf16 swz
    float* y    = (float*)(ws + 37748736);    // 16 MB fc output (pre-LN)

    float* out  = (float*)d_out;
    float* attn = out + (size_t)B_ * L_ * DMODEL_;

    prep_qk<<<2048, 256, 0, stream>>>(q, qb);
    prep_qk<<<2048, 256, 0, stream>>>(k, kb);
    prep_v <<<1024, 256, 0, stream>>>(v, vb);
    prep_w <<<512,  256, 0, stream>>>(W_fc, whi, wlo);

    attn_mfma<<<512, 512, 0, stream>>>(qb, kb, vb, attn, head);

    fc_mfma<<<dim3(16, 32), 512, 0, stream>>>(head, whi, wlo, b_fc, q, y);

    ln_kernel<<<1024, 256, 0, stream>>>(y, gamma, beta, out);
}